// Round 5
// baseline (171.947 us; speedup 1.0000x reference)
//
#include <hip/hip_runtime.h>
#include <hip/hip_bf16.h>

// B=2, S=2048, D=1024, H=16, DH=64. fp32 in/out; bf16 MFMA internals.
#define S_LEN   2048
#define D_MODEL 1024
#define N_HEADS 16
#define D_HEAD  64
#define HEAD_ELEMS (2048ull * 64ull)          // elements per (b,h) plane
#define MAT_ELEMS  (4096ull * 1024ull)        // one projected matrix (Q/K/V)
#define W_ELEMS    (1024ull * 1024ull)        // one weight matrix

typedef __attribute__((ext_vector_type(8))) short short8_t;   // 8 bf16
typedef __attribute__((ext_vector_type(4))) short short4_t;   // 4 bf16
typedef __attribute__((ext_vector_type(4))) float f32x4;      // MFMA C/D frag

__device__ __forceinline__ short f2bf(float f) {
    __hip_bfloat16 h = __float2bfloat16(f);
    union { __hip_bfloat16 h; short s; } cv;
    cv.h = h;
    return cv.s;
}

// global_load_lds width=16: LDS dest = wave-uniform base + lane*16
#define GLD_LDS16(gptr, lptr) \
    __builtin_amdgcn_global_load_lds( \
        (const __attribute__((address_space(1))) unsigned int*)(gptr), \
        (__attribute__((address_space(3))) unsigned int*)(lptr), 16, 0, 0)

// ---------------------------------------------------------------------------
// Kernel 0a: convert x fp32 -> bf16.
// ---------------------------------------------------------------------------
__global__ __launch_bounds__(256) void convert_x_kernel(
    const float* __restrict__ x, short* __restrict__ xb)
{
    const int i = (blockIdx.x * 256 + threadIdx.x) * 8;
    const float4 v0 = *(const float4*)(x + i);
    const float4 v1 = *(const float4*)(x + i + 4);
    short8_t u;
    u[0] = f2bf(v0.x); u[1] = f2bf(v0.y); u[2] = f2bf(v0.z); u[3] = f2bf(v0.w);
    u[4] = f2bf(v1.x); u[5] = f2bf(v1.y); u[6] = f2bf(v1.z); u[7] = f2bf(v1.w);
    *(short8_t*)(xb + i) = u;
}

// ---------------------------------------------------------------------------
// Kernel 0b: convert + transpose W fp32[k][n] -> bf16 Wt[n][k].
// ---------------------------------------------------------------------------
__global__ __launch_bounds__(256) void transpose_w_kernel(
    const float* __restrict__ Wq, const float* __restrict__ Wk,
    const float* __restrict__ Wv, short* __restrict__ wt)
{
    const int k0 = blockIdx.x * 64;
    const int n0 = blockIdx.y * 64;
    const int which = blockIdx.z;
    const float* W = (which == 0) ? Wq : (which == 1) ? Wk : Wv;
    short* out = wt + (size_t)which * W_ELEMS;

    __shared__ float Ts[64][68];   // [n_local][k_local]
    const int t = threadIdx.x;
    {
        const int c4 = (t & 15) * 4;
#pragma unroll
        for (int i = 0; i < 4; ++i) {
            const int r = (t >> 4) + i * 16;
            const float4 v = *(const float4*)(W + (size_t)(k0 + r) * D_MODEL + n0 + c4);
            Ts[c4 + 0][r] = v.x; Ts[c4 + 1][r] = v.y;
            Ts[c4 + 2][r] = v.z; Ts[c4 + 3][r] = v.w;
        }
    }
    __syncthreads();
    const int nl = t >> 2;
#pragma unroll
    for (int s = 0; s < 2; ++s) {
        const int koff = (t & 3) * 8 + s * 32;
        short8_t u;
#pragma unroll
        for (int j = 0; j < 8; ++j) u[j] = f2bf(Ts[nl][koff + j]);
        *(short8_t*)(out + (size_t)(n0 + nl) * D_MODEL + k0 + koff) = u;
    }
}

// ---------------------------------------------------------------------------
// Kernel 1: QKV GEMM (m97 structure). Q pre-scaled by (1/8)*log2(e) so the
// attention softmax can run in exp2 domain. Q/K epilogue round-trips through
// wave-private LDS for coalesced dwordx4 stores.
// ---------------------------------------------------------------------------
__global__ __launch_bounds__(256, 3) void qkv_mfma_gemm_kernel(
    const short* __restrict__ xb,
    const short* __restrict__ wt,
    short* __restrict__ qkv)
{
    const int mBlock = blockIdx.x * 128;
    const int nBlock = blockIdx.y * 128;
    const int which  = blockIdx.z;
    const short* Bt = wt + (size_t)which * W_ELEMS;
    short* outBase  = qkv + (size_t)which * MAT_ELEMS;

    __shared__ short As[128 * 32];               // [m][k] contiguous, 8 KB
    __shared__ short Bs[128 * 32];               // [n][k] contiguous, 8 KB
    __shared__ __align__(16) short Es[4][64 * 72]; // per-wave epilogue, 36 KB

    const int t    = threadIdx.x;
    const int w    = t >> 6;
    const int lane = t & 63;
    const int n16  = lane & 15;
    const int quad = lane >> 4;
    const int mq   = (w & 1) * 64;
    const int nq   = (w >> 1) * 64;

    f32x4 acc[4][4];
#pragma unroll
    for (int i = 0; i < 4; ++i)
#pragma unroll
        for (int j = 0; j < 4; ++j) acc[i][j] = (f32x4){0.f, 0.f, 0.f, 0.f};

    const int off0 = w * 2048 + lane * 16;       // bytes
    const int off1 = off0 + 1024;
    const int r0s = off0 >> 6, k0s = (off0 & 63) >> 1;
    const int r1s = off1 >> 6, k1s = (off1 & 63) >> 1;
    const short* gA0 = xb + (size_t)(mBlock + r0s) * D_MODEL + k0s;
    const short* gA1 = xb + (size_t)(mBlock + r1s) * D_MODEL + k1s;
    const short* gB0 = Bt + (size_t)(nBlock + r0s) * D_MODEL + k0s;
    const short* gB1 = Bt + (size_t)(nBlock + r1s) * D_MODEL + k1s;
    short* lA0 = As + w * 1024;
    short* lA1 = As + w * 1024 + 512;
    short* lB0 = Bs + w * 1024;
    short* lB1 = Bs + w * 1024 + 512;

    for (int k0 = 0; k0 < D_MODEL; k0 += 32) {
        __syncthreads();
        GLD_LDS16(gA0 + k0, lA0);
        GLD_LDS16(gA1 + k0, lA1);
        GLD_LDS16(gB0 + k0, lB0);
        GLD_LDS16(gB1 + k0, lB1);
        __syncthreads();

        short8_t af[4], bf[4];
#pragma unroll
        for (int mt = 0; mt < 4; ++mt)
            af[mt] = *(const short8_t*)&As[(mq + mt * 16 + n16) * 32 + quad * 8];
#pragma unroll
        for (int nt = 0; nt < 4; ++nt)
            bf[nt] = *(const short8_t*)&Bs[(nq + nt * 16 + n16) * 32 + quad * 8];
#pragma unroll
        for (int mt = 0; mt < 4; ++mt)
#pragma unroll
            for (int nt = 0; nt < 4; ++nt)
                acc[mt][nt] = __builtin_amdgcn_mfma_f32_16x16x32_bf16(
                    af[mt], bf[nt], acc[mt][nt], 0, 0, 0);
    }

    // fold 1/sqrt(DH) AND log2(e) into Q (softmax runs in exp2 domain)
    const float oscale = (which == 0) ? 0.125f * 1.44269504089f : 1.0f;
    if (which < 2) {
        // ---- stage bf16 tile in wave-private LDS [m_local][dh], pad 72 ----
        short* E = &Es[w][0];
#pragma unroll
        for (int mt = 0; mt < 4; ++mt)
#pragma unroll
            for (int nt = 0; nt < 4; ++nt) {
                const int dhl = nt * 16 + n16;
#pragma unroll
                for (int reg = 0; reg < 4; ++reg) {
                    const int ml = mt * 16 + quad * 4 + reg;
                    E[ml * 72 + dhl] = f2bf(acc[mt][nt][reg] * oscale);
                }
            }
        // wave-private: no barrier needed; lgkmcnt orders write->read
        const int h  = (nBlock + nq) >> 6;           // fixed per wave tile
        const int m0 = mBlock + mq;                  // 64-aligned
        const int bb = m0 >> 11, ss0 = m0 & 2047;    // tile never crosses b
        const int rsub = lane >> 3;                  // 0..7
        const int ch   = lane & 7;                   // 0..7 (16B chunk of dh)
        short* orow = outBase + ((size_t)(bb * N_HEADS + h) * S_LEN + ss0) * D_HEAD
                      + ch * 8;
#pragma unroll
        for (int it = 0; it < 8; ++it) {
            const int row = it * 8 + rsub;
            const short8_t v = *(const short8_t*)&E[row * 72 + ch * 8];
            *(short8_t*)(orow + (size_t)row * D_HEAD) = v;
        }
    } else {
        // V transposed (b,h,dh,s)
#pragma unroll
        for (int mt = 0; mt < 4; ++mt) {
            const int m0 = mBlock + mq + mt * 16 + quad * 4;
            const int bb = m0 >> 11, ss0 = m0 & 2047;
#pragma unroll
            for (int nt = 0; nt < 4; ++nt) {
                const int n = nBlock + nq + nt * 16 + n16;
                const int h = n >> 6, dh = n & 63;
                short4_t u;
                u[0] = f2bf(acc[mt][nt][0]); u[1] = f2bf(acc[mt][nt][1]);
                u[2] = f2bf(acc[mt][nt][2]); u[3] = f2bf(acc[mt][nt][3]);
                *(short4_t*)(outBase +
                    ((size_t)((bb * N_HEADS + h) * D_HEAD + dh)) * S_LEN + ss0) = u;
            }
        }
    }
}

// ---------------------------------------------------------------------------
// Kernel 2: causal flash attention via bf16 MFMA, v8.
// Post-mortems: per-CU tile-unit throughput was pinned (~0.6 units/kcycle)
// across v3/v4/v6/v7 — per-round overheads (staging, 2 barriers, phase-locked
// stalls) dominate. v8 amortizes them 2x: each wave owns TWO q-subtiles
// (QBLK=32/wave; A = rows r..r+15, B = r+64..r+79) over the SAME staged K/V
// tile. Block covers 128 q-rows; grid (32 bh x 16 q-blocks) unpaired, LPT
// (qb = 15 - y). Stagings per unit of work halve (528 -> 272 per bh).
// Causality: A diag @ tile 2qb, skipped @ 2qb+1; B diag @ 2qb+1.
// Keeps: staged XOR-swizzled K/V, 2-barrier tile loop, exp2-domain softmax,
// defer-max (T13), setprio (T5), LDS P round-trip, swizzled f32 epilogue.
// ---------------------------------------------------------------------------
__global__ __launch_bounds__(256, 4) void attn_mfma_kernel(
    const short* __restrict__ qkv,
    float* __restrict__ out)
{
    const int bh   = blockIdx.x;
    const int qb   = 15 - blockIdx.y;     // 128-row q-block, LPT order
    const int t    = threadIdx.x;
    const int w    = t >> 6;
    const int lane = t & 63;
    const int n    = lane & 15;
    const int quad = lane >> 4;

    const short* Q  = qkv + (size_t)bh * HEAD_ELEMS;
    const short* K  = qkv + MAT_ELEMS + (size_t)bh * HEAD_ELEMS;
    const short* Vt = qkv + 2 * MAT_ELEMS + (size_t)bh * HEAD_ELEMS;  // (dh,s)

    __shared__ __align__(16) short Ks[64 * 64];          // swizzled [row][chunk]
    __shared__ __align__(16) short Vs[64 * 64];          // swizzled [dh][chunk]
    __shared__ __align__(16) short Ps[4][16][72];        // per-wave P round-trip

    // --- staging: wave w stages rows [16w,16w+16) of K and V, 2 insts each ---
    const int srow0 = w * 16 + (lane >> 3);              // inst-0 row
    const int srow1 = srow0 + 8;                         // inst-1 row
    const int sd0 = ((lane & 7) ^ (srow0 & 7)) * 8;      // swizzled src offset
    const int sd1 = ((lane & 7) ^ (srow1 & 7)) * 8;
    const short* gK0 = K + srow0 * 64 + sd0;             // += j0*64 per tile
    const short* gK1 = K + srow1 * 64 + sd1;
    const short* gV0 = Vt + (size_t)srow0 * S_LEN + sd0; // += j0 per tile
    const short* gV1 = Vt + (size_t)srow1 * S_LEN + sd1;
    short* lK0 = Ks + (w * 16) * 64;
    short* lK1 = Ks + (w * 16 + 8) * 64;
    short* lV0 = Vs + (w * 16) * 64;
    short* lV1 = Vs + (w * 16 + 8) * 64;

    // frag-read physical chunk offset (shorts): a0 at pcK, a1 at pcK^32
    const int pcK = ((quad ^ (n & 7))) * 8;

    const int bb = bh >> 4;
    const int hh = bh & 15;

    const int r0a   = qb * 128 + w * 16;     // subtile 0 rows (first 64-half)
    const int qrow0 = r0a + n;
    const int qrow1 = qrow0 + 64;            // subtile 1 rows (second 64-half)

    // Q fragments for both subtiles (Q pre-scaled by log2e/8 in the GEMM)
    const short8_t bq00 = *(const short8_t*)(Q + (size_t)qrow0 * D_HEAD + quad * 8);
    const short8_t bq01 = *(const short8_t*)(Q + (size_t)qrow0 * D_HEAD + quad * 8 + 32);
    const short8_t bq10 = *(const short8_t*)(Q + (size_t)qrow1 * D_HEAD + quad * 8);
    const short8_t bq11 = *(const short8_t*)(Q + (size_t)qrow1 * D_HEAD + quad * 8 + 32);

    float mm[2] = {-__builtin_inff(), -__builtin_inff()};
    float ll[2] = {0.f, 0.f};
    f32x4 oo[2][4];
#pragma unroll
    for (int s = 0; s < 2; ++s)
#pragma unroll
        for (int f = 0; f < 4; ++f) oo[s][f] = (f32x4){0.f, 0.f, 0.f, 0.f};

    const int ntiles = 2 * qb + 2;
    for (int tg = 0; tg < ntiles; ++tg) {
        const int j0 = tg * 64;
        __syncthreads();                       // prior LDS reads done
        GLD_LDS16(gK0 + j0 * 64, lK0);
        GLD_LDS16(gK1 + j0 * 64, lK1);
        GLD_LDS16(gV0 + j0, lV0);
        GLD_LDS16(gV1 + j0, lV1);
        __syncthreads();                       // vmcnt drained by barrier

#pragma unroll
        for (int sub = 0; sub < 2; ++sub) {
            // subtile A contributes nothing on the block's last tile
            if (sub == 0 && tg == ntiles - 1) continue;
            const int qrow = sub ? qrow1 : qrow0;
            const short8_t bqa = sub ? bq10 : bq00;
            const short8_t bqb = sub ? bq11 : bq01;

            // ---- S^T = K_tile . Q^T ----
            f32x4 st[4];
            __builtin_amdgcn_s_setprio(1);
#pragma unroll
            for (int kg = 0; kg < 4; ++kg) {
                const int rbase = (kg * 16 + n) * 64;
                const short8_t a0 = *(const short8_t*)&Ks[rbase + pcK];
                const short8_t a1 = *(const short8_t*)&Ks[rbase + (pcK ^ 32)];
                f32x4 acc = (f32x4){0.f, 0.f, 0.f, 0.f};
                acc = __builtin_amdgcn_mfma_f32_16x16x32_bf16(a0, bqa, acc, 0, 0, 0);
                acc = __builtin_amdgcn_mfma_f32_16x16x32_bf16(a1, bqb, acc, 0, 0, 0);
                st[kg] = acc;
            }
            __builtin_amdgcn_s_setprio(0);

            // ---- online softmax in exp2 domain (mask only on diagonal) ----
            float p[16];
            float mx = -__builtin_inff();
            if (tg == 2 * qb + sub) {          // this subtile's diagonal tile
#pragma unroll
                for (int kg = 0; kg < 4; ++kg)
#pragma unroll
                    for (int r = 0; r < 4; ++r) {
                        const int key = j0 + kg * 16 + quad * 4 + r;
                        float s = st[kg][r];
                        s = (key <= qrow) ? s : -__builtin_inff();
                        p[kg * 4 + r] = s;
                        mx = fmaxf(mx, s);
                    }
            } else {
#pragma unroll
                for (int i = 0; i < 16; ++i) {
                    const float s = st[i >> 2][i & 3];
                    p[i] = s;
                    mx = fmaxf(mx, s);
                }
            }
            mx = fmaxf(mx, __shfl_xor(mx, 16));
            mx = fmaxf(mx, __shfl_xor(mx, 32));

            float ls = 0.f;
            if (__all(mx <= mm[sub] + 8.0f)) {
                // defer-max: keep old m, no rescale. P bounded by 2^8.
#pragma unroll
                for (int i = 0; i < 16; ++i) {
                    p[i] = __builtin_amdgcn_exp2f(p[i] - mm[sub]);
                    ls += p[i];
                }
                ls += __shfl_xor(ls, 16);
                ls += __shfl_xor(ls, 32);
                ll[sub] += ls;
            } else {
                const float mnew  = fmaxf(mm[sub], mx);
                const float alpha = __builtin_amdgcn_exp2f(mm[sub] - mnew);
#pragma unroll
                for (int i = 0; i < 16; ++i) {
                    p[i] = __builtin_amdgcn_exp2f(p[i] - mnew);
                    ls += p[i];
                }
                ls += __shfl_xor(ls, 16);
                ls += __shfl_xor(ls, 32);
                ll[sub] = ll[sub] * alpha + ls;
                mm[sub] = mnew;
#pragma unroll
                for (int f = 0; f < 4; ++f) {
                    oo[sub][f][0] *= alpha; oo[sub][f][1] *= alpha;
                    oo[sub][f][2] *= alpha; oo[sub][f][3] *= alpha;
                }
            }

            // ---- pack P -> bf16 by truncation, same-wave LDS round trip ----
#pragma unroll
            for (int kg = 0; kg < 4; ++kg) {
                const unsigned int b0 = __builtin_bit_cast(unsigned int, p[kg * 4 + 0]);
                const unsigned int b1 = __builtin_bit_cast(unsigned int, p[kg * 4 + 1]);
                const unsigned int b2 = __builtin_bit_cast(unsigned int, p[kg * 4 + 2]);
                const unsigned int b3 = __builtin_bit_cast(unsigned int, p[kg * 4 + 3]);
                uint2 pk;
                pk.x = (b0 >> 16) | (b1 & 0xffff0000u);
                pk.y = (b2 >> 16) | (b3 & 0xffff0000u);
                *(uint2*)&Ps[w][n][kg * 16 + quad * 4] = pk;
            }
            const short8_t pb0 = *(const short8_t*)&Ps[w][n][quad * 8];
            const short8_t pb1 = *(const short8_t*)&Ps[w][n][quad * 8 + 32];

            // ---- O^T += V^T_tile . P^T ----
            __builtin_amdgcn_s_setprio(1);
#pragma unroll
            for (int f = 0; f < 4; ++f) {
                const int rbase = (f * 16 + n) * 64;
                const short8_t va0 = *(const short8_t*)&Vs[rbase + pcK];
                const short8_t va1 = *(const short8_t*)&Vs[rbase + (pcK ^ 32)];
                oo[sub][f] = __builtin_amdgcn_mfma_f32_16x16x32_bf16(va0, pb0, oo[sub][f], 0, 0, 0);
                oo[sub][f] = __builtin_amdgcn_mfma_f32_16x16x32_bf16(va1, pb1, oo[sub][f], 0, 0, 0);
            }
            __builtin_amdgcn_s_setprio(0);
        }
    }

    // ---- epilogue: swizzled transpose through Ks/Vs, coalesced stores ----
    __syncthreads();   // all waves done reading Ks/Vs
    float* Os = (float*)((w < 2) ? (void*)Ks : (void*)Vs) + (w & 1) * 1024;
#pragma unroll
    for (int sub = 0; sub < 2; ++sub) {
        const float inv_l = 1.0f / ll[sub];
#pragma unroll
        for (int f = 0; f < 4; ++f) {
            const int c  = f * 4 + quad;          // logical 16B chunk (dh/4)
            const int pc = c ^ n;                 // physical chunk
            f32x4 q4;
            q4[0] = oo[sub][f][0] * inv_l; q4[1] = oo[sub][f][1] * inv_l;
            q4[2] = oo[sub][f][2] * inv_l; q4[3] = oo[sub][f][3] * inv_l;
            *(f32x4*)&Os[n * 64 + pc * 4] = q4;   // row n, dh chunk c
        }
#pragma unroll
        for (int rr = 0; rr < 4; ++rr) {
            const int row = rr * 4 + quad;        // q-row within wave tile
            const int pc  = n ^ row;              // logical chunk n, swizzled
            const f32x4 val = *(const f32x4*)&Os[row * 64 + pc * 4];
            *(f32x4*)(out + ((size_t)(bb * S_LEN + r0a + sub * 64 + row)) * D_MODEL
                          + hh * D_HEAD + n * 4) = val;
        }
        // same-wave DS ops execute in order -> safe to reuse Os for sub 1
    }
}

// ---------------------------------------------------------------------------
extern "C" void kernel_launch(void* const* d_in, const int* in_sizes, int n_in,
                              void* d_out, int out_size, void* d_ws, size_t ws_size,
                              hipStream_t stream) {
    const float* x  = (const float*)d_in[0];
    const float* Wq = (const float*)d_in[1];
    const float* Wk = (const float*)d_in[2];
    const float* Wv = (const float*)d_in[3];
    float* out = (float*)d_out;

    // workspace: xb (8MB) | wt (6MB) | qkv (24MB) = 38MB
    short* xb  = (short*)d_ws;
    short* wt  = xb + MAT_ELEMS;
    short* qkv = wt + 3 * W_ELEMS;

    convert_x_kernel<<<dim3(MAT_ELEMS / (256 * 8)), 256, 0, stream>>>(x, xb);
    transpose_w_kernel<<<dim3(16, 16, 3), 256, 0, stream>>>(Wq, Wk, Wv, wt);

    qkv_mfma_gemm_kernel<<<dim3(32, 8, 3), 256, 0, stream>>>(xb, wt, qkv);

    attn_mfma_kernel<<<dim3(32, 16), 256, 0, stream>>>(qkv, out);
}

// Round 6
// 148.738 us; speedup vs baseline: 1.1560x; 1.1560x over previous
//
#include <hip/hip_runtime.h>
#include <hip/hip_bf16.h>

// B=2, S=2048, D=1024, H=16, DH=64. fp32 in/out; bf16 MFMA internals.
#define S_LEN   2048
#define D_MODEL 1024
#define N_HEADS 16
#define D_HEAD  64
#define HEAD_ELEMS (2048ull * 64ull)          // elements per (b,h) plane
#define MAT_ELEMS  (4096ull * 1024ull)        // one projected matrix (Q/K/V)
#define W_ELEMS    (1024ull * 1024ull)        // one weight matrix

typedef __attribute__((ext_vector_type(8))) short short8_t;   // 8 bf16
typedef __attribute__((ext_vector_type(4))) short short4_t;   // 4 bf16
typedef __attribute__((ext_vector_type(4))) float f32x4;      // MFMA C/D frag

__device__ __forceinline__ short f2bf(float f) {
    __hip_bfloat16 h = __float2bfloat16(f);
    union { __hip_bfloat16 h; short s; } cv;
    cv.h = h;
    return cv.s;
}

// global_load_lds width=16: LDS dest = wave-uniform base + lane*16
#define GLD_LDS16(gptr, lptr) \
    __builtin_amdgcn_global_load_lds( \
        (const __attribute__((address_space(1))) unsigned int*)(gptr), \
        (__attribute__((address_space(3))) unsigned int*)(lptr), 16, 0, 0)

// ---------------------------------------------------------------------------
// Kernel 0a: convert x fp32 -> bf16.
// ---------------------------------------------------------------------------
__global__ __launch_bounds__(256) void convert_x_kernel(
    const float* __restrict__ x, short* __restrict__ xb)
{
    const int i = (blockIdx.x * 256 + threadIdx.x) * 8;
    const float4 v0 = *(const float4*)(x + i);
    const float4 v1 = *(const float4*)(x + i + 4);
    short8_t u;
    u[0] = f2bf(v0.x); u[1] = f2bf(v0.y); u[2] = f2bf(v0.z); u[3] = f2bf(v0.w);
    u[4] = f2bf(v1.x); u[5] = f2bf(v1.y); u[6] = f2bf(v1.z); u[7] = f2bf(v1.w);
    *(short8_t*)(xb + i) = u;
}

// ---------------------------------------------------------------------------
// Kernel 0b: convert + transpose W fp32[k][n] -> bf16 Wt[n][k].
// ---------------------------------------------------------------------------
__global__ __launch_bounds__(256) void transpose_w_kernel(
    const float* __restrict__ Wq, const float* __restrict__ Wk,
    const float* __restrict__ Wv, short* __restrict__ wt)
{
    const int k0 = blockIdx.x * 64;
    const int n0 = blockIdx.y * 64;
    const int which = blockIdx.z;
    const float* W = (which == 0) ? Wq : (which == 1) ? Wk : Wv;
    short* out = wt + (size_t)which * W_ELEMS;

    __shared__ float Ts[64][68];   // [n_local][k_local]
    const int t = threadIdx.x;
    {
        const int c4 = (t & 15) * 4;
#pragma unroll
        for (int i = 0; i < 4; ++i) {
            const int r = (t >> 4) + i * 16;
            const float4 v = *(const float4*)(W + (size_t)(k0 + r) * D_MODEL + n0 + c4);
            Ts[c4 + 0][r] = v.x; Ts[c4 + 1][r] = v.y;
            Ts[c4 + 2][r] = v.z; Ts[c4 + 3][r] = v.w;
        }
    }
    __syncthreads();
    const int nl = t >> 2;
#pragma unroll
    for (int s = 0; s < 2; ++s) {
        const int koff = (t & 3) * 8 + s * 32;
        short8_t u;
#pragma unroll
        for (int j = 0; j < 8; ++j) u[j] = f2bf(Ts[nl][koff + j]);
        *(short8_t*)(out + (size_t)(n0 + nl) * D_MODEL + k0 + koff) = u;
    }
}

// ---------------------------------------------------------------------------
// Kernel 1: QKV GEMM (m97 structure). Q pre-scaled by (1/8)*log2(e) so the
// attention softmax can run in exp2 domain. Q/K epilogue round-trips through
// wave-private LDS for coalesced dwordx4 stores.
// v9 change: V epilogue ALSO round-trips through the wave-private Es buffer
// ([dh][s] layout, pad 72) so its stores are 8 x dwordx4 along contiguous s
// (full 128B lines) instead of 16 scattered 8B stores at 4KB stride.
// ---------------------------------------------------------------------------
__global__ __launch_bounds__(256, 3) void qkv_mfma_gemm_kernel(
    const short* __restrict__ xb,
    const short* __restrict__ wt,
    short* __restrict__ qkv)
{
    const int mBlock = blockIdx.x * 128;
    const int nBlock = blockIdx.y * 128;
    const int which  = blockIdx.z;
    const short* Bt = wt + (size_t)which * W_ELEMS;
    short* outBase  = qkv + (size_t)which * MAT_ELEMS;

    __shared__ short As[128 * 32];               // [m][k] contiguous, 8 KB
    __shared__ short Bs[128 * 32];               // [n][k] contiguous, 8 KB
    __shared__ __align__(16) short Es[4][64 * 72]; // per-wave epilogue, 36 KB

    const int t    = threadIdx.x;
    const int w    = t >> 6;
    const int lane = t & 63;
    const int n16  = lane & 15;
    const int quad = lane >> 4;
    const int mq   = (w & 1) * 64;
    const int nq   = (w >> 1) * 64;

    f32x4 acc[4][4];
#pragma unroll
    for (int i = 0; i < 4; ++i)
#pragma unroll
        for (int j = 0; j < 4; ++j) acc[i][j] = (f32x4){0.f, 0.f, 0.f, 0.f};

    const int off0 = w * 2048 + lane * 16;       // bytes
    const int off1 = off0 + 1024;
    const int r0s = off0 >> 6, k0s = (off0 & 63) >> 1;
    const int r1s = off1 >> 6, k1s = (off1 & 63) >> 1;
    const short* gA0 = xb + (size_t)(mBlock + r0s) * D_MODEL + k0s;
    const short* gA1 = xb + (size_t)(mBlock + r1s) * D_MODEL + k1s;
    const short* gB0 = Bt + (size_t)(nBlock + r0s) * D_MODEL + k0s;
    const short* gB1 = Bt + (size_t)(nBlock + r1s) * D_MODEL + k1s;
    short* lA0 = As + w * 1024;
    short* lA1 = As + w * 1024 + 512;
    short* lB0 = Bs + w * 1024;
    short* lB1 = Bs + w * 1024 + 512;

    for (int k0 = 0; k0 < D_MODEL; k0 += 32) {
        __syncthreads();
        GLD_LDS16(gA0 + k0, lA0);
        GLD_LDS16(gA1 + k0, lA1);
        GLD_LDS16(gB0 + k0, lB0);
        GLD_LDS16(gB1 + k0, lB1);
        __syncthreads();

        short8_t af[4], bf[4];
#pragma unroll
        for (int mt = 0; mt < 4; ++mt)
            af[mt] = *(const short8_t*)&As[(mq + mt * 16 + n16) * 32 + quad * 8];
#pragma unroll
        for (int nt = 0; nt < 4; ++nt)
            bf[nt] = *(const short8_t*)&Bs[(nq + nt * 16 + n16) * 32 + quad * 8];
#pragma unroll
        for (int mt = 0; mt < 4; ++mt)
#pragma unroll
            for (int nt = 0; nt < 4; ++nt)
                acc[mt][nt] = __builtin_amdgcn_mfma_f32_16x16x32_bf16(
                    af[mt], bf[nt], acc[mt][nt], 0, 0, 0);
    }

    // fold 1/sqrt(DH) AND log2(e) into Q (softmax runs in exp2 domain)
    const float oscale = (which == 0) ? 0.125f * 1.44269504089f : 1.0f;
    short* E = &Es[w][0];
    const int h  = (nBlock + nq) >> 6;           // head: fixed per wave tile
    const int m0 = mBlock + mq;                  // 64-aligned
    const int bb = m0 >> 11, ss0 = m0 & 2047;    // tile never crosses b
    const int rsub = lane >> 3;                  // 0..7
    const int ch   = lane & 7;                   // 0..7 (16B chunk)

    if (which < 2) {
        // ---- stage bf16 tile in wave-private LDS [s_local][dh], pad 72 ----
#pragma unroll
        for (int mt = 0; mt < 4; ++mt)
#pragma unroll
            for (int nt = 0; nt < 4; ++nt) {
                const int dhl = nt * 16 + n16;
#pragma unroll
                for (int reg = 0; reg < 4; ++reg) {
                    const int ml = mt * 16 + quad * 4 + reg;
                    E[ml * 72 + dhl] = f2bf(acc[mt][nt][reg] * oscale);
                }
            }
        // wave-private: no barrier needed; lgkmcnt orders write->read
        short* orow = outBase + ((size_t)(bb * N_HEADS + h) * S_LEN + ss0) * D_HEAD
                      + ch * 8;
#pragma unroll
        for (int it = 0; it < 8; ++it) {
            const int row = it * 8 + rsub;       // s_local
            const short8_t v = *(const short8_t*)&E[row * 72 + ch * 8];
            *(short8_t*)(orow + (size_t)row * D_HEAD) = v;
        }
    } else {
        // ---- V transposed (b,h,dh,s): stage [dh_local][s_local], pad 72 ----
#pragma unroll
        for (int mt = 0; mt < 4; ++mt)
#pragma unroll
            for (int nt = 0; nt < 4; ++nt) {
                const int dhl = nt * 16 + n16;
                const int sl0 = mt * 16 + quad * 4;
                short4_t u;
                u[0] = f2bf(acc[mt][nt][0]); u[1] = f2bf(acc[mt][nt][1]);
                u[2] = f2bf(acc[mt][nt][2]); u[3] = f2bf(acc[mt][nt][3]);
                *(short4_t*)&E[dhl * 72 + sl0] = u;
            }
        // coalesced: 8 lanes x 16B = 128B contiguous in s per dh-row
        short* orow = outBase + ((size_t)(bb * N_HEADS + h) * D_HEAD) * S_LEN
                      + ss0 + ch * 8;
#pragma unroll
        for (int it = 0; it < 8; ++it) {
            const int dhl = it * 8 + rsub;       // dh_local 0..63
            const short8_t v = *(const short8_t*)&E[dhl * 72 + ch * 8];
            *(short8_t*)(orow + (size_t)dhl * S_LEN) = v;
        }
    }
}

// ---------------------------------------------------------------------------
// Kernel 2: causal flash attention via bf16 MFMA, v7 (reverted from v8).
// Empirical law across v3-v8: elapsed ~= Nrounds x (OH + k*C), OH~2.2k cy
// (staging+barriers+phase-lock), C~1.35k cy per 16-row subtile chain.
// v7 minimizes Nrounds without lengthening the per-block serial chain:
// 512 threads = TWO independent 4-wave groups; per round, group g
// stages+computes tile 2*round+g into its own Ks/Vs buffers. Partials
// merged flash-decoding-style at pass end (one extra barrier pair).
// Keeps: exp2-domain softmax, defer-max (T13), setprio (T5), XOR swizzle.
// ---------------------------------------------------------------------------
__global__ __launch_bounds__(512, 4) void attn_mfma_kernel(
    const short* __restrict__ qkv,
    float* __restrict__ out)
{
    const int bh   = blockIdx.x;
    const int pr   = blockIdx.y;          // pair index 0..15
    const int t    = threadIdx.x;         // 0..511
    const int w    = t >> 6;              // 0..7
    const int g    = w >> 2;              // tile-group 0/1
    const int wl   = w & 3;               // wave-in-group 0..3
    const int lane = t & 63;
    const int n    = lane & 15;
    const int quad = lane >> 4;

    const short* Q  = qkv + (size_t)bh * HEAD_ELEMS;
    const short* K  = qkv + MAT_ELEMS + (size_t)bh * HEAD_ELEMS;
    const short* Vt = qkv + 2 * MAT_ELEMS + (size_t)bh * HEAD_ELEMS;  // (dh,s)

    __shared__ __align__(16) short Ks[2][64 * 64];       // per-group K, 16 KB
    __shared__ __align__(16) short Vs[2][64 * 64];       // per-group V, 16 KB
    __shared__ __align__(16) short Ps[8][16][72];        // per-wave P round-trip
    __shared__ float Ml[2][64];                          // per-group m partial
    __shared__ float Ll[2][64];                          // per-group l partial

    // --- staging: group-wave wl stages rows [16wl,16wl+16) of K and V ---
    const int srow0 = wl * 16 + (lane >> 3);             // inst-0 row
    const int srow1 = srow0 + 8;                         // inst-1 row
    const int sd0 = ((lane & 7) ^ (srow0 & 7)) * 8;      // swizzled src offset
    const int sd1 = ((lane & 7) ^ (srow1 & 7)) * 8;
    const short* gK0 = K + srow0 * 64 + sd0;             // += j0*64 per tile
    const short* gK1 = K + srow1 * 64 + sd1;
    const short* gV0 = Vt + (size_t)srow0 * S_LEN + sd0; // += j0 per tile
    const short* gV1 = Vt + (size_t)srow1 * S_LEN + sd1;
    short* lK0 = &Ks[g][(wl * 16) * 64];
    short* lK1 = &Ks[g][(wl * 16 + 8) * 64];
    short* lV0 = &Vs[g][(wl * 16) * 64];
    short* lV1 = &Vs[g][(wl * 16 + 8) * 64];

    // frag-read physical chunk offset (shorts): a0 at pcK, a1 at pcK^32
    const int pcK = ((quad ^ (n & 7))) * 8;

    const int bb = bh >> 4;
    const int hh = bh & 15;

    for (int pass = 0; pass < 2; ++pass) {
        const int qb = pass ? (31 - pr) : pr;
        const int r0 = qb * 64 + wl * 16;      // both groups cover same q-rows
        const int qrow = r0 + n;

        const short8_t bq0 = *(const short8_t*)(Q + (size_t)qrow * D_HEAD + quad * 8);
        const short8_t bq1 = *(const short8_t*)(Q + (size_t)qrow * D_HEAD + quad * 8 + 32);

        float m = -__builtin_inff();
        float l = 0.f;
        f32x4 o[4];
#pragma unroll
        for (int f = 0; f < 4; ++f) o[f] = (f32x4){0.f, 0.f, 0.f, 0.f};

        const int nrounds = (qb + 2) >> 1;     // ceil((qb+1)/2)
        for (int rd = 0; rd < nrounds; ++rd) {
            const int tg = rd * 2 + g;         // this group's tile
            const bool have = (tg <= qb);
            const int j0 = tg * 64;

            __syncthreads();                   // prior LDS reads done
            if (have) {
                GLD_LDS16(gK0 + j0 * 64, lK0);
                GLD_LDS16(gK1 + j0 * 64, lK1);
                GLD_LDS16(gV0 + j0, lV0);
                GLD_LDS16(gV1 + j0, lV1);
            }
            __syncthreads();                   // vmcnt drained by barrier

            if (!have) continue;               // idle group still hit barriers

            // ---- S^T = K_tile . Q^T (Q pre-scaled by log2e/8) ----
            f32x4 st[4];
            __builtin_amdgcn_s_setprio(1);
#pragma unroll
            for (int kg = 0; kg < 4; ++kg) {
                const int rbase = (kg * 16 + n) * 64;
                const short8_t a0 = *(const short8_t*)&Ks[g][rbase + pcK];
                const short8_t a1 = *(const short8_t*)&Ks[g][rbase + (pcK ^ 32)];
                f32x4 acc = (f32x4){0.f, 0.f, 0.f, 0.f};
                acc = __builtin_amdgcn_mfma_f32_16x16x32_bf16(a0, bq0, acc, 0, 0, 0);
                acc = __builtin_amdgcn_mfma_f32_16x16x32_bf16(a1, bq1, acc, 0, 0, 0);
                st[kg] = acc;
            }
            __builtin_amdgcn_s_setprio(0);

            // ---- online softmax in exp2 domain (mask only on diagonal) ----
            float p[16];
            float mx = -__builtin_inff();
            if (tg == qb) {
#pragma unroll
                for (int kg = 0; kg < 4; ++kg)
#pragma unroll
                    for (int r = 0; r < 4; ++r) {
                        const int key = j0 + kg * 16 + quad * 4 + r;
                        float s = st[kg][r];
                        s = (key <= qrow) ? s : -__builtin_inff();
                        p[kg * 4 + r] = s;
                        mx = fmaxf(mx, s);
                    }
            } else {
#pragma unroll
                for (int i = 0; i < 16; ++i) {
                    const float s = st[i >> 2][i & 3];
                    p[i] = s;
                    mx = fmaxf(mx, s);
                }
            }
            mx = fmaxf(mx, __shfl_xor(mx, 16));
            mx = fmaxf(mx, __shfl_xor(mx, 32));

            float ls = 0.f;
            if (__all(mx <= m + 8.0f)) {
                // defer-max: keep old m, no rescale. P bounded by 2^8.
#pragma unroll
                for (int i = 0; i < 16; ++i) {
                    p[i] = __builtin_amdgcn_exp2f(p[i] - m);
                    ls += p[i];
                }
                ls += __shfl_xor(ls, 16);
                ls += __shfl_xor(ls, 32);
                l += ls;
            } else {
                const float mnew  = fmaxf(m, mx);
                const float alpha = __builtin_amdgcn_exp2f(m - mnew);
#pragma unroll
                for (int i = 0; i < 16; ++i) {
                    p[i] = __builtin_amdgcn_exp2f(p[i] - mnew);
                    ls += p[i];
                }
                ls += __shfl_xor(ls, 16);
                ls += __shfl_xor(ls, 32);
                l = l * alpha + ls;
                m = mnew;
#pragma unroll
                for (int f = 0; f < 4; ++f) {
                    o[f][0] *= alpha; o[f][1] *= alpha;
                    o[f][2] *= alpha; o[f][3] *= alpha;
                }
            }

            // ---- pack P -> bf16 by truncation, same-wave LDS round trip ----
#pragma unroll
            for (int kg = 0; kg < 4; ++kg) {
                const unsigned int b0 = __builtin_bit_cast(unsigned int, p[kg * 4 + 0]);
                const unsigned int b1 = __builtin_bit_cast(unsigned int, p[kg * 4 + 1]);
                const unsigned int b2 = __builtin_bit_cast(unsigned int, p[kg * 4 + 2]);
                const unsigned int b3 = __builtin_bit_cast(unsigned int, p[kg * 4 + 3]);
                uint2 pk;
                pk.x = (b0 >> 16) | (b1 & 0xffff0000u);
                pk.y = (b2 >> 16) | (b3 & 0xffff0000u);
                *(uint2*)&Ps[w][n][kg * 16 + quad * 4] = pk;
            }
            const short8_t pb0 = *(const short8_t*)&Ps[w][n][quad * 8];
            const short8_t pb1 = *(const short8_t*)&Ps[w][n][quad * 8 + 32];

            // ---- O^T += V^T_tile . P^T ----
            __builtin_amdgcn_s_setprio(1);
#pragma unroll
            for (int f = 0; f < 4; ++f) {
                const int rbase = (f * 16 + n) * 64;
                const short8_t va0 = *(const short8_t*)&Vs[g][rbase + pcK];
                const short8_t va1 = *(const short8_t*)&Vs[g][rbase + (pcK ^ 32)];
                o[f] = __builtin_amdgcn_mfma_f32_16x16x32_bf16(va0, pb0, o[f], 0, 0, 0);
                o[f] = __builtin_amdgcn_mfma_f32_16x16x32_bf16(va1, pb1, o[f], 0, 0, 0);
            }
            __builtin_amdgcn_s_setprio(0);
        }

        // ---- merge the two group partials (flash-decoding combine) ----
        __syncthreads();   // all staging-buffer reads done
        // group 0 partial -> Ks area (16 KB f32), group 1 -> Vs area.
        // wave region wl*1024 floats; row n, logical chunk c at pc = c^n.
        {
            float* Og = (float*)(g == 0 ? (void*)Ks : (void*)Vs) + wl * 1024;
#pragma unroll
            for (int f = 0; f < 4; ++f) {
                const int c  = f * 4 + quad;
                const int pc = c ^ n;
                *(f32x4*)&Og[n * 64 + pc * 4] = o[f];   // raw partial (no 1/l)
            }
            if (quad == 0) {
                Ml[g][wl * 16 + n] = m;
                Ll[g][wl * 16 + n] = l;
            }
        }
        __syncthreads();
        // combine + store: thread t handles (row = t>>3, 8-float chunk c8 = t&7)
        {
            const int row = t >> 3;              // 0..63
            const int c8  = t & 7;               // 0..7
            const int wr  = row >> 4;            // owning wave region
            const int nr_ = row & 15;
            const float m0 = Ml[0][row], m1 = Ml[1][row];
            const float l0 = Ll[0][row], l1 = Ll[1][row];
            const float M  = fmaxf(m0, m1);
            const float a0 = __builtin_amdgcn_exp2f(m0 - M);
            const float a1 = __builtin_amdgcn_exp2f(m1 - M);
            const float inv = 1.0f / (l0 * a0 + l1 * a1);
            const float* O0 = (const float*)Ks + wr * 1024;
            const float* O1 = (const float*)Vs + wr * 1024;
            float* op = out + ((size_t)(bb * S_LEN + qb * 64 + row)) * D_MODEL
                        + hh * D_HEAD + c8 * 8;
#pragma unroll
            for (int cc = 0; cc < 2; ++cc) {
                const int c  = c8 * 2 + cc;      // logical chunk 0..15
                const int pc = c ^ nr_;
                const f32x4 x0 = *(const f32x4*)&O0[nr_ * 64 + pc * 4];
                const f32x4 x1 = *(const f32x4*)&O1[nr_ * 64 + pc * 4];
                f32x4 r;
                r[0] = (x0[0] * a0 + x1[0] * a1) * inv;
                r[1] = (x0[1] * a0 + x1[1] * a1) * inv;
                r[2] = (x0[2] * a0 + x1[2] * a1) * inv;
                r[3] = (x0[3] * a0 + x1[3] * a1) * inv;
                *(f32x4*)(op + cc * 4) = r;
            }
        }
        // next pass's first round begins with __syncthreads -> safe to restage
    }
}

// ---------------------------------------------------------------------------
extern "C" void kernel_launch(void* const* d_in, const int* in_sizes, int n_in,
                              void* d_out, int out_size, void* d_ws, size_t ws_size,
                              hipStream_t stream) {
    const float* x  = (const float*)d_in[0];
    const float* Wq = (const float*)d_in[1];
    const float* Wk = (const float*)d_in[2];
    const float* Wv = (const float*)d_in[3];
    float* out = (float*)d_out;

    // workspace: xb (8MB) | wt (6MB) | qkv (24MB) = 38MB
    short* xb  = (short*)d_ws;
    short* wt  = xb + MAT_ELEMS;
    short* qkv = wt + 3 * W_ELEMS;

    convert_x_kernel<<<dim3(MAT_ELEMS / (256 * 8)), 256, 0, stream>>>(x, xb);
    transpose_w_kernel<<<dim3(16, 16, 3), 256, 0, stream>>>(Wq, Wk, Wv, wt);

    qkv_mfma_gemm_kernel<<<dim3(32, 8, 3), 256, 0, stream>>>(xb, wt, qkv);

    attn_mfma_kernel<<<dim3(2 * N_HEADS, 16), 512, 0, stream>>>(qkv, out);
}